// Round 1
// baseline (499.690 us; speedup 1.0000x reference)
//
#include <hip/hip_runtime.h>

#define L_DIM 4096
#define H_DIM 16
#define E_DIM 64
#define BH 128
#define ROWSTRIDE 1024  // H_DIM*E_DIM floats between consecutive l

#define P1_CHUNK 512
#define P2_CHUNK 512

__device__ __forceinline__ float inv_softplus_temp(const float* delta1) {
  // temp = softplus(delta1); return 1/temp
  return 1.0f / log1pf(__expf(delta1[0]));
}

// Phase 1: per (b,h) accumulate KV[d][e] = sum_l ktil[l][d] * v[l][e], ksum[d] = sum_l ktil[l][d]
__global__ __launch_bounds__(256) void p1_kv(
    const float* __restrict__ Kp, const float* __restrict__ Vp,
    const float* __restrict__ delta1,
    float* __restrict__ ws_kv, float* __restrict__ ws_ksum) {
  const int t = threadIdx.x;
  const int bh = blockIdx.y;
  const int b = bh >> 4, h = bh & 15;
  const int lane = t & 63;
  const int w = t >> 6;
  const float inv_temp = inv_softplus_temp(delta1);
  const size_t base = ((size_t)b * L_DIM * H_DIM + h) * E_DIM;
  const int l0 = blockIdx.x * P1_CHUNK;

  __shared__ float sk[16][64];
  __shared__ float sv[16][64];

  const int rsub = lane >> 4;           // 0..3: row within this wave's group of 4
  const int equad = (lane & 15) << 2;   // e-offset 0,4,...,60
  const int srow = (w << 2) | rsub;     // 0..15: row slot in LDS

  const int d0 = (t >> 4) << 2;         // k-feature tile base, 0..60
  const int e0 = (t & 15) << 2;         // v-feature tile base, 0..60

  float acc[4][4];
  float ks[4];
#pragma unroll
  for (int i = 0; i < 4; ++i) {
    ks[i] = 0.f;
#pragma unroll
    for (int j = 0; j < 4; ++j) acc[i][j] = 0.f;
  }

  for (int it = 0; it < P1_CHUNK / 16; ++it) {
    const int l = l0 + it * 16 + srow;
    const float4 k4 = *(const float4*)(Kp + base + (size_t)l * ROWSTRIDE + equad);
    const float4 v4 = *(const float4*)(Vp + base + (size_t)l * ROWSTRIDE + equad);
    // exp((clamp_neg_to_-20)/temp); no max-subtraction needed: x <= ~9 -> exp fits fp32 easily
    float ex = __expf((k4.x < 0.f ? -20.f : k4.x) * inv_temp);
    float ey = __expf((k4.y < 0.f ? -20.f : k4.y) * inv_temp);
    float ez = __expf((k4.z < 0.f ? -20.f : k4.z) * inv_temp);
    float ew = __expf((k4.w < 0.f ? -20.f : k4.w) * inv_temp);
    float s = ex + ey + ez + ew;
    // row lives in a 16-lane group (lane>>4 constant); xor masks 1,2,4,8 stay in-group
    s += __shfl_xor(s, 1);
    s += __shfl_xor(s, 2);
    s += __shfl_xor(s, 4);
    s += __shfl_xor(s, 8);
    const float rs = __builtin_amdgcn_rcpf(s);

    __syncthreads();  // previous iteration's LDS reads complete (WAR)
    *(float4*)&sk[srow][equad] = make_float4(ex * rs, ey * rs, ez * rs, ew * rs);
    *(float4*)&sv[srow][equad] = v4;
    __syncthreads();  // stores visible

#pragma unroll
    for (int rr = 0; rr < 16; ++rr) {
      const float4 kk = *(const float4*)&sk[rr][d0];
      const float4 vv = *(const float4*)&sv[rr][e0];
      const float ka[4] = {kk.x, kk.y, kk.z, kk.w};
      const float va[4] = {vv.x, vv.y, vv.z, vv.w};
#pragma unroll
      for (int i = 0; i < 4; ++i)
#pragma unroll
        for (int j = 0; j < 4; ++j)
          acc[i][j] = fmaf(ka[i], va[j], acc[i][j]);
      if (e0 == 0) {
        ks[0] += ka[0]; ks[1] += ka[1]; ks[2] += ka[2]; ks[3] += ka[3];
      }
    }
  }

  float* kvdst = ws_kv + (size_t)bh * 4096;
#pragma unroll
  for (int i = 0; i < 4; ++i)
#pragma unroll
    for (int j = 0; j < 4; ++j)
      atomicAdd(&kvdst[(d0 + i) * 64 + (e0 + j)], acc[i][j]);
  if (e0 == 0) {
#pragma unroll
    for (int i = 0; i < 4; ++i)
      atomicAdd(&ws_ksum[bh * 64 + d0 + i], ks[i]);
  }
}

// Phase 2: out[l][d] = sum_e w[l][e] * KV[e][d],  w = Eq / (Eq.ksum + eps*sum(Eq))
__global__ __launch_bounds__(256) void p2_out(
    const float* __restrict__ Qp, const float* __restrict__ delta1,
    const float* __restrict__ ws_kv, const float* __restrict__ ws_ksum,
    float* __restrict__ outp) {
  const int t = threadIdx.x;
  const int bh = blockIdx.y;
  const int b = bh >> 4, h = bh & 15;
  const int lane = t & 63;
  const int w = t >> 6;
  const float inv_temp = inv_softplus_temp(delta1);
  const size_t base = ((size_t)b * L_DIM * H_DIM + h) * E_DIM;
  const int l0 = blockIdx.x * P2_CHUNK;

  const int rsub = lane >> 4;
  const int equad = (lane & 15) << 2;

  // KV column for my output feature d=lane, all 64 contraction features, in registers
  float kvcol[64];
#pragma unroll
  for (int e = 0; e < 64; ++e)
    kvcol[e] = ws_kv[(size_t)bh * 4096 + e * 64 + lane];

  const float4 ks4 = *(const float4*)&ws_ksum[bh * 64 + equad];

  __shared__ float sWT[4][64][4];  // [wave][e][row-in-group]

  for (int it = 0; it < P2_CHUNK / 16; ++it) {
    const int l = l0 + it * 16 + (w << 2) + rsub;
    const float4 q4 = *(const float4*)(Qp + base + (size_t)l * ROWSTRIDE + equad);
    float ex = __expf((q4.x < 0.f ? -20.f : q4.x) * inv_temp);
    float ey = __expf((q4.y < 0.f ? -20.f : q4.y) * inv_temp);
    float ez = __expf((q4.z < 0.f ? -20.f : q4.z) * inv_temp);
    float ew = __expf((q4.w < 0.f ? -20.f : q4.w) * inv_temp);
    float sE = ex + ey + ez + ew;
    float sD = ex * ks4.x + ey * ks4.y + ez * ks4.z + ew * ks4.w;
    sE += __shfl_xor(sE, 1); sD += __shfl_xor(sD, 1);
    sE += __shfl_xor(sE, 2); sD += __shfl_xor(sD, 2);
    sE += __shfl_xor(sE, 4); sD += __shfl_xor(sD, 4);
    sE += __shfl_xor(sE, 8); sD += __shfl_xor(sD, 8);
    // w = E / (E.ksum + eps*S)  ==  z * softmax(q)  exactly (eps semantics preserved)
    const float scale = __builtin_amdgcn_rcpf(sD + 1e-6f * sE);

    __syncthreads();  // WAR vs previous iteration's reads
    sWT[w][equad + 0][rsub] = ex * scale;
    sWT[w][equad + 1][rsub] = ey * scale;
    sWT[w][equad + 2][rsub] = ez * scale;
    sWT[w][equad + 3][rsub] = ew * scale;
    __syncthreads();

    float a0 = 0.f, a1 = 0.f, a2 = 0.f, a3 = 0.f;
#pragma unroll
    for (int e = 0; e < 64; ++e) {
      const float4 wv = *(const float4*)&sWT[w][e][0];  // broadcast b128
      const float kve = kvcol[e];
      a0 = fmaf(wv.x, kve, a0);
      a1 = fmaf(wv.y, kve, a1);
      a2 = fmaf(wv.z, kve, a2);
      a3 = fmaf(wv.w, kve, a3);
    }

    const size_t ob = base + (size_t)(l0 + it * 16 + (w << 2)) * ROWSTRIDE + lane;
    outp[ob] = a0;
    outp[ob + ROWSTRIDE] = a1;
    outp[ob + 2 * (size_t)ROWSTRIDE] = a2;
    outp[ob + 3 * (size_t)ROWSTRIDE] = a3;
  }
}

extern "C" void kernel_launch(void* const* d_in, const int* in_sizes, int n_in,
                              void* d_out, int out_size, void* d_ws, size_t ws_size,
                              hipStream_t stream) {
  (void)in_sizes; (void)n_in; (void)out_size; (void)ws_size;
  const float* Q = (const float*)d_in[0];
  const float* K = (const float*)d_in[1];
  const float* V = (const float*)d_in[2];
  const float* delta1 = (const float*)d_in[3];
  float* out = (float*)d_out;

  float* ws_kv = (float*)d_ws;                       // BH * 64 * 64
  float* ws_ksum = ws_kv + (size_t)BH * 4096;        // BH * 64
  const size_t zero_bytes = ((size_t)BH * 4096 + (size_t)BH * 64) * sizeof(float);
  hipMemsetAsync(d_ws, 0, zero_bytes, stream);

  dim3 blk(256);
  dim3 g1(L_DIM / P1_CHUNK, BH);
  p1_kv<<<g1, blk, 0, stream>>>(K, V, delta1, ws_kv, ws_ksum);
  dim3 g2(L_DIM / P2_CHUNK, BH);
  p2_out<<<g2, blk, 0, stream>>>(Q, delta1, ws_kv, ws_ksum, out);
}